// Round 3
// baseline (2824.215 us; speedup 1.0000x reference)
//
#include <hip/hip_runtime.h>
#include <hip/hip_bf16.h>
#include <cstddef>
#include <cstdint>

// ---------------------------------------------------------------------------
// GPT forward, bf16-MFMA GEMMs + fp32 everything-else.
// B=8, T=512 (incl. cond token), D=768, H=12, dh=64, L=8, V=512, 4D=3072
// ---------------------------------------------------------------------------

#define NTOK 4096
#define TSEQ 512
#define DMODEL 768
#define DFF 3072
#define NHEAD 12
#define DHEAD 64
#define NLAYER 8
#define VOCAB 512
#define QKVD 2304  // 3*DMODEL fused QKV width

typedef __attribute__((ext_vector_type(8))) __bf16 bf16x8;
typedef __attribute__((ext_vector_type(4))) float f32x4;
typedef __attribute__((ext_vector_type(4))) unsigned int u32x4;
typedef __attribute__((ext_vector_type(4))) unsigned short u16x4;

__device__ __forceinline__ unsigned short f2bf(float f) {
  union { float f; unsigned int u; } v; v.f = f;
  return (unsigned short)((v.u + 0x7FFFu + ((v.u >> 16) & 1u)) >> 16);  // RNE
}

__device__ __forceinline__ float gelu_exact(float x) {
  return 0.5f * x * (1.f + erff(x * 0.70710678118654752f));
}

// direct global->LDS, 16B/lane, wave-uniform LDS base + lane*16
__device__ __forceinline__ void gload_lds16(const void* g, void* lds) {
  __builtin_amdgcn_global_load_lds(
      reinterpret_cast<__attribute__((address_space(1))) void*>(
          reinterpret_cast<uintptr_t>(g)),
      reinterpret_cast<__attribute__((address_space(3))) void*>(
          reinterpret_cast<uintptr_t>(lds)),
      16, 0, 0);
}

// ---------------- embedding (fp32) ----------------
__global__ __launch_bounds__(256) void embed_k(
    const int* __restrict__ idx, const int* __restrict__ cond,
    const float* __restrict__ tok, const float* __restrict__ ce,
    const float* __restrict__ te, const float* __restrict__ pe,
    float* __restrict__ X) {
  int row = blockIdx.x;  // b*512 + t
  int b = row >> 9, t = row & 511;
  int tid = threadIdx.x;
  const float* src = (t == 0) ? (ce + (size_t)cond[b] * DMODEL)
                              : (tok + (size_t)idx[b * 511 + t - 1] * DMODEL);
  const float* ty = te + (t != 0 ? DMODEL : 0);
  const float* pp = pe + (size_t)t * DMODEL;
  float* dst = X + (size_t)row * DMODEL;
#pragma unroll
  for (int i = 0; i < 3; i++) {
    int d = tid + i * 256;
    dst[d] = src[d] + pp[d] + ty[d];
  }
}

// ---------------- layernorm: fp32 in, bf16 out (+optional fp32 out) --------
template <bool F32OUT>
__global__ __launch_bounds__(256) void ln_k(
    const float* __restrict__ X, const float* __restrict__ g,
    const float* __restrict__ bta, float* __restrict__ O,
    unsigned short* __restrict__ Ob) {
  const int row = blockIdx.x;
  const int tid = threadIdx.x;
  const float* x = X + (size_t)row * DMODEL;
  float v0 = x[tid], v1 = x[tid + 256], v2 = x[tid + 512];
  float s = v0 + v1 + v2;
  float ss = v0 * v0 + v1 * v1 + v2 * v2;
#pragma unroll
  for (int o = 32; o > 0; o >>= 1) {
    s += __shfl_down(s, o);
    ss += __shfl_down(ss, o);
  }
  __shared__ float sm[8];
  const int wid = tid >> 6, lane = tid & 63;
  if (lane == 0) { sm[wid] = s; sm[wid + 4] = ss; }
  __syncthreads();
  float st = sm[0] + sm[1] + sm[2] + sm[3];
  float sst = sm[4] + sm[5] + sm[6] + sm[7];
  float mean = st * (1.f / DMODEL);
  float var = sst * (1.f / DMODEL) - mean * mean;
  float rstd = rsqrtf(var + 1e-5f);
  float y0 = (v0 - mean) * rstd * g[tid] + bta[tid];
  float y1 = (v1 - mean) * rstd * g[tid + 256] + bta[tid + 256];
  float y2 = (v2 - mean) * rstd * g[tid + 512] + bta[tid + 512];
  if (F32OUT) {
    float* o = O + (size_t)row * DMODEL;
    o[tid] = y0; o[tid + 256] = y1; o[tid + 512] = y2;
  }
  unsigned short* ob = Ob + (size_t)row * DMODEL;
  ob[tid] = f2bf(y0); ob[tid + 256] = f2bf(y1); ob[tid + 512] = f2bf(y2);
}

// ---------------- weight convert+transpose: fp32 [K][N] -> bf16 [N][K] -----
struct P4 { const float* p[4]; };

__global__ __launch_bounds__(256) void transp_k(P4 src,
                                                unsigned short* __restrict__ out,
                                                int K, int N) {
  __shared__ float Ls[64][65];
  const float* W = src.p[blockIdx.z];
  unsigned short* o = out + (size_t)blockIdx.z * K * N;
  const int tid = threadIdx.x;
  const int n0 = blockIdx.x * 64, k0 = blockIdx.y * 64;
  const int r = tid >> 4, c4 = (tid & 15) * 4;
#pragma unroll
  for (int i = 0; i < 4; i++) {
    const int kk = r + i * 16;
    const float4 v = *(const float4*)(W + (size_t)(k0 + kk) * N + n0 + c4);
    Ls[c4 + 0][kk] = v.x;
    Ls[c4 + 1][kk] = v.y;
    Ls[c4 + 2][kk] = v.z;
    Ls[c4 + 3][kk] = v.w;
  }
  __syncthreads();
#pragma unroll
  for (int i = 0; i < 4; i++) {
    const int nn = r + i * 16;
    u16x4 q;
    q.x = f2bf(Ls[nn][c4 + 0]);
    q.y = f2bf(Ls[nn][c4 + 1]);
    q.z = f2bf(Ls[nn][c4 + 2]);
    q.w = f2bf(Ls[nn][c4 + 3]);
    *(u16x4*)(o + (size_t)(n0 + nn) * K + k0 + c4) = q;
  }
}

// ---------------- pack per-layer QKV biases: [L][2304] ----------------
__global__ __launch_bounds__(256) void packb_k(const float* __restrict__ bq,
                                               const float* __restrict__ bk,
                                               const float* __restrict__ bv,
                                               float* __restrict__ o) {
  const int l = blockIdx.x, tid = threadIdx.x;
#pragma unroll
  for (int i = 0; i < 9; i++) {
    int n = tid + i * 256;
    float v = (n < 768) ? bq[l * 768 + n]
                        : (n < 1536) ? bk[l * 768 + n - 768]
                                     : bv[l * 768 + n - 1536];
    o[l * QKVD + n] = v;
  }
}

// ---------------- bf16 MFMA GEMM ----------------
// C[M,N] = A[M,K](bf16) @ Bt[N,K](bf16)^T, fp32 accumulate.
// TBMxTBN tile, BK=32, 256 thr = 4 waves in 2x2, each wave (TBM/2)x(TBN/2) of
// 16x16x32 frags. Staging via global_load_lds w=16 into [rows][32]-bf16 tiles
// with a 16B-chunk XOR swizzle (chunk ^= row&3) applied on BOTH the per-lane
// global source and the ds_read_b128 address (rule #21, same involution).
#define BK 32

constexpr int EPQ = 0;     // C f32 = acc + bias
constexpr int EPRES = 1;   // C f32 = acc + bias + res
constexpr int EPGELU = 2;  // C bf16 = gelu(acc + bias)
constexpr int EPHEAD = 3;  // C f32, row b*511+t-1 (skip t==0), no bias

template <int EP, int TBM, int TBN>
__global__ __launch_bounds__(256) void mm_k(
    const unsigned short* __restrict__ A, const unsigned short* __restrict__ Bt,
    const float* __restrict__ bias, const float* __restrict__ res,
    void* __restrict__ Cv, int K, int N) {
  __shared__ unsigned short As[TBM * BK];
  __shared__ unsigned short Bs[TBN * BK];
  constexpr int WM = TBM / 2, WN = TBN / 2;   // per-wave output tile
  constexpr int MI = WM / 16, NJ = WN / 16;   // fragment repeats
  const int tid = threadIdx.x;
  const int lane = tid & 63, wid = tid >> 6;
  const int wr = wid >> 1, wc = wid & 1;
  const int m0 = blockIdx.x * TBM, n0 = blockIdx.y * TBN;

  f32x4 acc[MI][NJ];
#pragma unroll
  for (int i = 0; i < MI; i++)
#pragma unroll
    for (int j = 0; j < NJ; j++) acc[i][j] = f32x4{0.f, 0.f, 0.f, 0.f};

  const int srow = lane >> 2;               // staging row within 16-row issue
  const int gch = (lane & 3) ^ (srow & 3);  // pre-swizzled 16B chunk
  const size_t rb = (size_t)K * 2;          // row bytes (A and Bt both K-wide)
  const int fr = lane & 15, ks = lane >> 4; // fragment row, k-subchunk

  for (int k0 = 0; k0 < K; k0 += BK) {
#pragma unroll
    for (int t = 0; t < TBM / 64; t++) {
      const int rr = wid * (TBM / 4) + t * 16;  // wave-uniform row base
      gload_lds16((const char*)A + (size_t)(m0 + rr + srow) * rb +
                      (size_t)k0 * 2 + gch * 16,
                  As + rr * BK);
    }
#pragma unroll
    for (int t = 0; t < TBN / 64; t++) {
      const int rr = wid * (TBN / 4) + t * 16;
      gload_lds16((const char*)Bt + (size_t)(n0 + rr + srow) * rb +
                      (size_t)k0 * 2 + gch * 16,
                  Bs + rr * BK);
    }
    __syncthreads();  // compiler drains vmcnt before barrier

    u32x4 ar[MI], br[NJ];
#pragma unroll
    for (int i = 0; i < MI; i++) {
      const int ra = wr * WM + i * 16 + fr;
      ar[i] = *(const u32x4*)((const char*)As + ra * 64 + ((ks ^ (ra & 3)) << 4));
    }
#pragma unroll
    for (int j = 0; j < NJ; j++) {
      const int rbw = wc * WN + j * 16 + fr;
      br[j] = *(const u32x4*)((const char*)Bs + rbw * 64 + ((ks ^ (rbw & 3)) << 4));
    }
#pragma unroll
    for (int i = 0; i < MI; i++)
#pragma unroll
      for (int j = 0; j < NJ; j++)
        acc[i][j] = __builtin_amdgcn_mfma_f32_16x16x32_bf16(
            __builtin_bit_cast(bf16x8, ar[i]), __builtin_bit_cast(bf16x8, br[j]),
            acc[i][j], 0, 0, 0);
    __syncthreads();
  }

  // epilogue: D[row=(lane>>4)*4+r][col=lane&15] per 16x16 fragment (m89)
#pragma unroll
  for (int i = 0; i < MI; i++) {
#pragma unroll
    for (int j = 0; j < NJ; j++) {
      const int n = n0 + wc * WN + j * 16 + fr;
      float bv = 0.f;
      if (EP != EPHEAD) bv = bias[n];
#pragma unroll
      for (int r = 0; r < 4; r++) {
        const int m = m0 + wr * WM + i * 16 + ks * 4 + r;
        float v = acc[i][j][r] + bv;
        if (EP == EPRES) v += res[(size_t)m * N + n];
        if (EP == EPGELU) {
          ((unsigned short*)Cv)[(size_t)m * N + n] = f2bf(gelu_exact(v));
        } else if (EP == EPHEAD) {
          const int bb = m >> 9, tt = m & 511;
          if (tt)
            ((float*)Cv)[(size_t)(bb * 511 + tt - 1) * N + n] = v;
        } else {
          ((float*)Cv)[(size_t)m * N + n] = v;
        }
      }
    }
  }
}

// ---------------- fused causal attention (flash-style, fp32, bf16 out) -----
// grid: (qtile 0..7, head 0..11, batch 0..7); 256 thr = 64 q-rows x 4 d-splits.
// Q/K/V live in the fused qkv buffer with row stride ldq.
__global__ __launch_bounds__(256) void attn_k(
    const float* __restrict__ Q, const float* __restrict__ K,
    const float* __restrict__ V, unsigned short* __restrict__ Y, int ldq) {
  __shared__ float Ks[64][64];
  __shared__ float Vs[64][64];
  const int qt = blockIdx.x, h = blockIdx.y, b = blockIdx.z;
  const int tid = threadIdx.x;
  const int rl = tid >> 2, ds = tid & 3;
  const int r = qt * 64 + rl;
  const int d0 = ds * 16;
  const size_t rowq = ((size_t)(b * TSEQ + r)) * ldq + h * DHEAD;

  float q[16];
#pragma unroll
  for (int i = 0; i < 4; i++)
    *(float4*)&q[i * 4] = *(const float4*)(Q + rowq + d0 + i * 4);

  float m = -1e30f, l = 0.f, acc[16];
#pragma unroll
  for (int i = 0; i < 16; i++) acc[i] = 0.f;
  const float scale = 0.125f;  // 1/sqrt(64)

  const int ntiles = qt + 1;  // causal
  for (int kt = 0; kt < ntiles; kt++) {
#pragma unroll
    for (int i = 0; i < 4; i++) {
      int f4 = tid + i * 256;
      int rk = f4 >> 4, c4 = (f4 & 15) * 4;
      size_t gg = ((size_t)(b * TSEQ + kt * 64 + rk)) * ldq + h * DHEAD + c4;
      *(float4*)&Ks[rk][c4] = *(const float4*)(K + gg);
      *(float4*)&Vs[rk][c4] = *(const float4*)(V + gg);
    }
    __syncthreads();
    const int jmax = min(64, r - kt * 64 + 1);
    for (int j = 0; j < 64; j++) {
      float kf[16];
      *(float4*)&kf[0]  = *(const float4*)&Ks[j][d0];
      *(float4*)&kf[4]  = *(const float4*)&Ks[j][d0 + 4];
      *(float4*)&kf[8]  = *(const float4*)&Ks[j][d0 + 8];
      *(float4*)&kf[12] = *(const float4*)&Ks[j][d0 + 12];
      float s = 0.f;
#pragma unroll
      for (int i = 0; i < 16; i++) s = fmaf(q[i], kf[i], s);
      s += __shfl_xor(s, 1);
      s += __shfl_xor(s, 2);  // 4 d-split lanes now agree
      s *= scale;
      if (j < jmax) {
        float mn = fmaxf(m, s);
        float corr = __expf(m - mn);
        float p = __expf(s - mn);
        l = l * corr + p;
        float vf[16];
        *(float4*)&vf[0]  = *(const float4*)&Vs[j][d0];
        *(float4*)&vf[4]  = *(const float4*)&Vs[j][d0 + 4];
        *(float4*)&vf[8]  = *(const float4*)&Vs[j][d0 + 8];
        *(float4*)&vf[12] = *(const float4*)&Vs[j][d0 + 12];
#pragma unroll
        for (int i = 0; i < 16; i++) acc[i] = fmaf(acc[i], corr, p * vf[i]);
        m = mn;
      }
    }
    __syncthreads();
  }
  const float inv = 1.f / l;
  const size_t rowy = ((size_t)(b * TSEQ + r)) * DMODEL + h * DHEAD;
  alignas(16) unsigned short ob[16];
#pragma unroll
  for (int i = 0; i < 16; i++) ob[i] = f2bf(acc[i] * inv);
  *(u32x4*)(Y + rowy + d0) = *(const u32x4*)&ob[0];
  *(u32x4*)(Y + rowy + d0 + 8) = *(const u32x4*)&ob[8];
}

// ---------------------------------------------------------------------------
extern "C" void kernel_launch(void* const* d_in, const int* in_sizes, int n_in,
                              void* d_out, int out_size, void* d_ws, size_t ws_size,
                              hipStream_t stream) {
  const int* idx = (const int*)d_in[0];
  const int* condition = (const int*)d_in[1];
  const float* tok_emb = (const float*)d_in[2];
  const float* cond_emb = (const float*)d_in[3];
  const float* type_emb = (const float*)d_in[4];
  const float* pos_emb = (const float*)d_in[5];
  const float* ln1_g = (const float*)d_in[6];
  const float* ln1_b = (const float*)d_in[7];
  const float* Wq = (const float*)d_in[8];
  const float* bq = (const float*)d_in[9];
  const float* Wk = (const float*)d_in[10];
  const float* bk = (const float*)d_in[11];
  const float* Wv = (const float*)d_in[12];
  const float* bv = (const float*)d_in[13];
  const float* Wp = (const float*)d_in[14];
  const float* bp = (const float*)d_in[15];
  const float* ln2_g = (const float*)d_in[16];
  const float* ln2_b = (const float*)d_in[17];
  const float* W1 = (const float*)d_in[18];
  const float* b1 = (const float*)d_in[19];
  const float* W2 = (const float*)d_in[20];
  const float* b2 = (const float*)d_in[21];
  const float* lnf_g = (const float*)d_in[22];
  const float* lnf_b = (const float*)d_in[23];
  const float* head_w = (const float*)d_in[24];

  const size_t WDD = (size_t)DMODEL * DMODEL;
  const size_t WDF = (size_t)DMODEL * DFF;
  const size_t SD = (size_t)NTOK * DMODEL;

  // workspace layout (~91 MB)
  char* wp = (char*)d_ws;
  auto alloc = [&](size_t bytes) {
    char* r = wp;
    wp += (bytes + 255) & ~(size_t)255;
    return r;
  };
  float* x = (float*)alloc(SD * 4);
  float* h = (float*)alloc(SD * 4);
  unsigned short* hb = (unsigned short*)alloc(SD * 2);
  float* qkv = (float*)alloc((size_t)NTOK * QKVD * 4);  // fused QKV out (37.7MB)
  unsigned short* yb = (unsigned short*)alloc(SD * 2);
  unsigned short* lw = (unsigned short*)alloc((4 * WDD + 2 * WDF) * 2);
  unsigned short* headt = (unsigned short*)alloc((size_t)VOCAB * DMODEL * 2);
  float* qkvb = (float*)alloc((size_t)NLAYER * QKVD * 4);
  unsigned short* m1b = (unsigned short*)qkv;  // [NTOK][DFF] bf16 overlay (25MB)

  unsigned short* lwQKV = lw;            // 2304 rows x K=768 (Q,K,V contiguous)
  unsigned short* lwP = lw + 3 * WDD;
  unsigned short* lw1 = lw + 4 * WDD;
  unsigned short* lw2 = lw + 4 * WDD + WDF;

  embed_k<<<NTOK, 256, 0, stream>>>(idx, condition, tok_emb, cond_emb,
                                    type_emb, pos_emb, x);
  packb_k<<<NLAYER, 256, 0, stream>>>(bq, bk, bv, qkvb);
  {  // head_w [768][512] -> [512][768] bf16, once
    P4 s{{head_w, nullptr, nullptr, nullptr}};
    transp_k<<<dim3(VOCAB / 64, DMODEL / 64, 1), 256, 0, stream>>>(
        s, headt, DMODEL, VOCAB);
  }

  const dim3 gQKV(NTOK / 128, QKVD / 128);  // 32 x 18 = 576 blocks
  const dim3 gDD64(NTOK / 64, DMODEL / 64); // 64 x 12 = 768 blocks
  const dim3 gDF(NTOK / 128, DFF / 128);    // 32 x 24 = 768 blocks
  const dim3 gDV(NTOK / 64, VOCAB / 64);    // 64 x 8  = 512 blocks

  for (int l = 0; l < NLAYER; l++) {
    {  // JIT convert+transpose this layer's weights into lw
      P4 s{{Wq + l * WDD, Wk + l * WDD, Wv + l * WDD, Wp + l * WDD}};
      transp_k<<<dim3(12, 12, 4), 256, 0, stream>>>(s, lw, DMODEL, DMODEL);
      P4 s1{{W1 + l * WDF, nullptr, nullptr, nullptr}};
      transp_k<<<dim3(48, 12, 1), 256, 0, stream>>>(s1, lw1, DMODEL, DFF);
      P4 s2{{W2 + l * WDF, nullptr, nullptr, nullptr}};
      transp_k<<<dim3(12, 48, 1), 256, 0, stream>>>(s2, lw2, DFF, DMODEL);
    }
    ln_k<true><<<NTOK, 256, 0, stream>>>(x, ln1_g + l * DMODEL,
                                         ln1_b + l * DMODEL, h, hb);
    // fused QKV: [NTOK,768] @ [2304,768]^T -> [NTOK,2304]
    mm_k<EPQ, 128, 128><<<gQKV, 256, 0, stream>>>(
        hb, lwQKV, qkvb + l * QKVD, nullptr, qkv, DMODEL, QKVD);
    attn_k<<<dim3(8, NHEAD, 8), 256, 0, stream>>>(
        qkv, qkv + DMODEL, qkv + 2 * DMODEL, yb, QKVD);
    // x = h + y @ Wp + bp  (residual base is post-ln1 h, per reference quirk)
    mm_k<EPRES, 64, 64><<<gDD64, 256, 0, stream>>>(
        yb, lwP, bp + l * DMODEL, h, x, DMODEL, DMODEL);
    ln_k<false><<<NTOK, 256, 0, stream>>>(x, ln2_g + l * DMODEL,
                                          ln2_b + l * DMODEL, nullptr, hb);
    mm_k<EPGELU, 128, 128><<<gDF, 256, 0, stream>>>(
        hb, lw1, b1 + l * DFF, nullptr, m1b, DMODEL, DFF);
    // x = x + m1 @ W2 + b2 (in-place: each element read+written by same thread)
    mm_k<EPRES, 64, 64><<<gDD64, 256, 0, stream>>>(
        m1b, lw2, b2 + l * DMODEL, x, x, DFF, DMODEL);
  }

  ln_k<false><<<NTOK, 256, 0, stream>>>(x, lnf_g, lnf_b, nullptr, hb);
  mm_k<EPHEAD, 64, 64><<<gDV, 256, 0, stream>>>(
      hb, headt, nullptr, nullptr, d_out, DMODEL, VOCAB);
}

// Round 4
// 1672.271 us; speedup vs baseline: 1.6889x; 1.6889x over previous
//
#include <hip/hip_runtime.h>
#include <hip/hip_bf16.h>
#include <cstddef>
#include <cstdint>

// ---------------------------------------------------------------------------
// GPT forward: bf16 MFMA GEMMs + bf16 MFMA flash attention; fp32 LN/softmax.
// B=8, T=512 (incl. cond token), D=768, H=12, dh=64, L=8, V=512, 4D=3072
// ---------------------------------------------------------------------------

#define NTOK 4096
#define TSEQ 512
#define DMODEL 768
#define DFF 3072
#define NHEAD 12
#define DHEAD 64
#define NLAYER 8
#define VOCAB 512
#define QKVD 2304  // 3*DMODEL fused QKV width

typedef __attribute__((ext_vector_type(8))) __bf16 bf16x8;
typedef __attribute__((ext_vector_type(4))) float f32x4;
typedef __attribute__((ext_vector_type(4))) unsigned int u32x4;
typedef __attribute__((ext_vector_type(4))) unsigned short u16x4;

__device__ __forceinline__ unsigned short f2bf(float f) {
  union { float f; unsigned int u; } v; v.f = f;
  return (unsigned short)((v.u + 0x7FFFu + ((v.u >> 16) & 1u)) >> 16);  // RNE
}

__device__ __forceinline__ float gelu_exact(float x) {
  return 0.5f * x * (1.f + erff(x * 0.70710678118654752f));
}

// direct global->LDS, 16B/lane, wave-uniform LDS base + lane*16
__device__ __forceinline__ void gload_lds16(const void* g, void* lds) {
  __builtin_amdgcn_global_load_lds(
      reinterpret_cast<__attribute__((address_space(1))) void*>(
          reinterpret_cast<uintptr_t>(g)),
      reinterpret_cast<__attribute__((address_space(3))) void*>(
          reinterpret_cast<uintptr_t>(lds)),
      16, 0, 0);
}

// ---------------- embedding (fp32) ----------------
__global__ __launch_bounds__(256) void embed_k(
    const int* __restrict__ idx, const int* __restrict__ cond,
    const float* __restrict__ tok, const float* __restrict__ ce,
    const float* __restrict__ te, const float* __restrict__ pe,
    float* __restrict__ X) {
  int row = blockIdx.x;  // b*512 + t
  int b = row >> 9, t = row & 511;
  int tid = threadIdx.x;
  const float* src = (t == 0) ? (ce + (size_t)cond[b] * DMODEL)
                              : (tok + (size_t)idx[b * 511 + t - 1] * DMODEL);
  const float* ty = te + (t != 0 ? DMODEL : 0);
  const float* pp = pe + (size_t)t * DMODEL;
  float* dst = X + (size_t)row * DMODEL;
#pragma unroll
  for (int i = 0; i < 3; i++) {
    int d = tid + i * 256;
    dst[d] = src[d] + pp[d] + ty[d];
  }
}

// ---------------- layernorm: fp32 in, bf16 out (+optional fp32 out) --------
template <bool F32OUT>
__global__ __launch_bounds__(256) void ln_k(
    const float* __restrict__ X, const float* __restrict__ g,
    const float* __restrict__ bta, float* __restrict__ O,
    unsigned short* __restrict__ Ob) {
  const int row = blockIdx.x;
  const int tid = threadIdx.x;
  const float* x = X + (size_t)row * DMODEL;
  float v0 = x[tid], v1 = x[tid + 256], v2 = x[tid + 512];
  float s = v0 + v1 + v2;
  float ss = v0 * v0 + v1 * v1 + v2 * v2;
#pragma unroll
  for (int o = 32; o > 0; o >>= 1) {
    s += __shfl_down(s, o);
    ss += __shfl_down(ss, o);
  }
  __shared__ float sm[8];
  const int wid = tid >> 6, lane = tid & 63;
  if (lane == 0) { sm[wid] = s; sm[wid + 4] = ss; }
  __syncthreads();
  float st = sm[0] + sm[1] + sm[2] + sm[3];
  float sst = sm[4] + sm[5] + sm[6] + sm[7];
  float mean = st * (1.f / DMODEL);
  float var = sst * (1.f / DMODEL) - mean * mean;
  float rstd = rsqrtf(var + 1e-5f);
  float y0 = (v0 - mean) * rstd * g[tid] + bta[tid];
  float y1 = (v1 - mean) * rstd * g[tid + 256] + bta[tid + 256];
  float y2 = (v2 - mean) * rstd * g[tid + 512] + bta[tid + 512];
  if (F32OUT) {
    float* o = O + (size_t)row * DMODEL;
    o[tid] = y0; o[tid + 256] = y1; o[tid + 512] = y2;
  }
  unsigned short* ob = Ob + (size_t)row * DMODEL;
  ob[tid] = f2bf(y0); ob[tid + 256] = f2bf(y1); ob[tid + 512] = f2bf(y2);
}

// ---------------- weight convert+transpose: fp32 [K][N] -> bf16 [N][K] -----
struct P4 { const float* p[4]; };

__global__ __launch_bounds__(256) void transp_k(P4 src,
                                                unsigned short* __restrict__ out,
                                                int K, int N) {
  __shared__ float Ls[64][65];
  const float* W = src.p[blockIdx.z];
  unsigned short* o = out + (size_t)blockIdx.z * K * N;
  const int tid = threadIdx.x;
  const int n0 = blockIdx.x * 64, k0 = blockIdx.y * 64;
  const int r = tid >> 4, c4 = (tid & 15) * 4;
#pragma unroll
  for (int i = 0; i < 4; i++) {
    const int kk = r + i * 16;
    const float4 v = *(const float4*)(W + (size_t)(k0 + kk) * N + n0 + c4);
    Ls[c4 + 0][kk] = v.x;
    Ls[c4 + 1][kk] = v.y;
    Ls[c4 + 2][kk] = v.z;
    Ls[c4 + 3][kk] = v.w;
  }
  __syncthreads();
#pragma unroll
  for (int i = 0; i < 4; i++) {
    const int nn = r + i * 16;
    u16x4 q;
    q.x = f2bf(Ls[nn][c4 + 0]);
    q.y = f2bf(Ls[nn][c4 + 1]);
    q.z = f2bf(Ls[nn][c4 + 2]);
    q.w = f2bf(Ls[nn][c4 + 3]);
    *(u16x4*)(o + (size_t)(n0 + nn) * K + k0 + c4) = q;
  }
}

// ---------------- pack per-layer QKV biases: [L][2304] ----------------
__global__ __launch_bounds__(256) void packb_k(const float* __restrict__ bq,
                                               const float* __restrict__ bk,
                                               const float* __restrict__ bv,
                                               float* __restrict__ o) {
  const int l = blockIdx.x, tid = threadIdx.x;
#pragma unroll
  for (int i = 0; i < 9; i++) {
    int n = tid + i * 256;
    float v = (n < 768) ? bq[l * 768 + n]
                        : (n < 1536) ? bk[l * 768 + n - 768]
                                     : bv[l * 768 + n - 1536];
    o[l * QKVD + n] = v;
  }
}

// ---------------- bf16 MFMA GEMM ----------------
// C[M,N] = A[M,K](bf16) @ Bt[N,K](bf16)^T, fp32 accumulate.
#define BK 32

constexpr int EPQ = 0;     // C f32 = acc + bias
constexpr int EPRES = 1;   // C f32 = acc + bias + res
constexpr int EPGELU = 2;  // C bf16 = gelu(acc + bias)
constexpr int EPHEAD = 3;  // C f32, row b*511+t-1 (skip t==0), no bias
constexpr int EPQB = 4;    // C bf16 = acc + bias

template <int EP, int TBM, int TBN>
__global__ __launch_bounds__(256) void mm_k(
    const unsigned short* __restrict__ A, const unsigned short* __restrict__ Bt,
    const float* __restrict__ bias, const float* __restrict__ res,
    void* __restrict__ Cv, int K, int N) {
  __shared__ unsigned short As[TBM * BK];
  __shared__ unsigned short Bs[TBN * BK];
  constexpr int WM = TBM / 2, WN = TBN / 2;   // per-wave output tile
  constexpr int MI = WM / 16, NJ = WN / 16;   // fragment repeats
  const int tid = threadIdx.x;
  const int lane = tid & 63, wid = tid >> 6;
  const int wr = wid >> 1, wc = wid & 1;
  const int m0 = blockIdx.x * TBM, n0 = blockIdx.y * TBN;

  f32x4 acc[MI][NJ];
#pragma unroll
  for (int i = 0; i < MI; i++)
#pragma unroll
    for (int j = 0; j < NJ; j++) acc[i][j] = f32x4{0.f, 0.f, 0.f, 0.f};

  const int srow = lane >> 2;               // staging row within 16-row issue
  const int gch = (lane & 3) ^ (srow & 3);  // pre-swizzled 16B chunk
  const size_t rb = (size_t)K * 2;          // row bytes (A and Bt both K-wide)
  const int fr = lane & 15, ks = lane >> 4; // fragment row, k-subchunk

  for (int k0 = 0; k0 < K; k0 += BK) {
#pragma unroll
    for (int t = 0; t < TBM / 64; t++) {
      const int rr = wid * (TBM / 4) + t * 16;  // wave-uniform row base
      gload_lds16((const char*)A + (size_t)(m0 + rr + srow) * rb +
                      (size_t)k0 * 2 + gch * 16,
                  As + rr * BK);
    }
#pragma unroll
    for (int t = 0; t < TBN / 64; t++) {
      const int rr = wid * (TBN / 4) + t * 16;
      gload_lds16((const char*)Bt + (size_t)(n0 + rr + srow) * rb +
                      (size_t)k0 * 2 + gch * 16,
                  Bs + rr * BK);
    }
    __syncthreads();  // compiler drains vmcnt before barrier

    u32x4 ar[MI], br[NJ];
#pragma unroll
    for (int i = 0; i < MI; i++) {
      const int ra = wr * WM + i * 16 + fr;
      ar[i] = *(const u32x4*)((const char*)As + ra * 64 + ((ks ^ (ra & 3)) << 4));
    }
#pragma unroll
    for (int j = 0; j < NJ; j++) {
      const int rbw = wc * WN + j * 16 + fr;
      br[j] = *(const u32x4*)((const char*)Bs + rbw * 64 + ((ks ^ (rbw & 3)) << 4));
    }
#pragma unroll
    for (int i = 0; i < MI; i++)
#pragma unroll
      for (int j = 0; j < NJ; j++)
        acc[i][j] = __builtin_amdgcn_mfma_f32_16x16x32_bf16(
            __builtin_bit_cast(bf16x8, ar[i]), __builtin_bit_cast(bf16x8, br[j]),
            acc[i][j], 0, 0, 0);
    __syncthreads();
  }

  // epilogue: D[row=(lane>>4)*4+r][col=lane&15] per 16x16 fragment (m89)
#pragma unroll
  for (int i = 0; i < MI; i++) {
#pragma unroll
    for (int j = 0; j < NJ; j++) {
      const int n = n0 + wc * WN + j * 16 + fr;
      float bv = 0.f;
      if (EP != EPHEAD) bv = bias[n];
#pragma unroll
      for (int r = 0; r < 4; r++) {
        const int m = m0 + wr * WM + i * 16 + ks * 4 + r;
        float v = acc[i][j][r] + bv;
        if (EP == EPRES) v += res[(size_t)m * N + n];
        if (EP == EPGELU) {
          ((unsigned short*)Cv)[(size_t)m * N + n] = f2bf(gelu_exact(v));
        } else if (EP == EPQB) {
          ((unsigned short*)Cv)[(size_t)m * N + n] = f2bf(v);
        } else if (EP == EPHEAD) {
          const int bb = m >> 9, tt = m & 511;
          if (tt)
            ((float*)Cv)[(size_t)(bb * 511 + tt - 1) * N + n] = v;
        } else {
          ((float*)Cv)[(size_t)m * N + n] = v;
        }
      }
    }
  }
}

// ---------------- bf16 MFMA flash attention ----------------
// grid (8 qtiles, 12 heads, 8 batch), 256 thr = 4 waves; wave wq owns q-rows
// [qt*64 + wq*16, +16). Per 64-key tile: stage K [64][72] and V^T [64][72] in
// LDS (bf16, pad->144B stride: 16B-aligned, ~2-way banks = free), QK^T via
// 8 MFMAs, fp32 online softmax in C-layout regs (row r on a 16-lane group ->
// shfl_xor 1/2/4/8 row-reduce), P->LDS bf16, PV via 8 MFMAs with corr rescale.
__global__ __launch_bounds__(256) void attn_mfma_k(
    const unsigned short* __restrict__ QKV, unsigned short* __restrict__ Y) {
  __shared__ unsigned short Ks[64][72];
  __shared__ unsigned short Vt[64][72];
  __shared__ unsigned short Pl[4][16][72];
  const int qt = 7 - (int)blockIdx.x;  // heavy blocks first (less tail)
  const int h = blockIdx.y, b = blockIdx.z;
  const int tid = threadIdx.x;
  const int lane = tid & 63, wq = tid >> 6;
  const int fr = lane & 15, g = lane >> 4;

  // Q fragments (A operand): row = wq*16+fr, d = st*32 + g*8 .. +7
  const size_t qrow =
      (size_t)(b * TSEQ + qt * 64 + wq * 16 + fr) * QKVD + h * DHEAD;
  u32x4 qf[2];
  qf[0] = *(const u32x4*)(QKV + qrow + g * 8);
  qf[1] = *(const u32x4*)(QKV + qrow + 32 + g * 8);

  f32x4 of[4];
  float m[4], l[4];
#pragma unroll
  for (int jd = 0; jd < 4; jd++) of[jd] = f32x4{0.f, 0.f, 0.f, 0.f};
#pragma unroll
  for (int r = 0; r < 4; r++) { m[r] = -1e30f; l[r] = 0.f; }

  const int srow = tid >> 2, sc = (tid & 3) * 16;  // staging row / 16-col chunk

  for (int kt = 0; kt <= qt; kt++) {
    {  // stage K tile and transposed V tile
      const size_t kr = (size_t)(b * TSEQ + kt * 64 + srow) * QKVD + h * DHEAD;
      u32x4 k0 = *(const u32x4*)(QKV + kr + DMODEL + sc);
      u32x4 k1 = *(const u32x4*)(QKV + kr + DMODEL + sc + 8);
      *(u32x4*)&Ks[srow][sc] = k0;
      *(u32x4*)&Ks[srow][sc + 8] = k1;
      u32x4 v0 = *(const u32x4*)(QKV + kr + 2 * DMODEL + sc);
      u32x4 v1 = *(const u32x4*)(QKV + kr + 2 * DMODEL + sc + 8);
      const unsigned short* vp = (const unsigned short*)&v0;
#pragma unroll
      for (int i = 0; i < 8; i++) Vt[sc + i][srow] = vp[i];
      vp = (const unsigned short*)&v1;
#pragma unroll
      for (int i = 0; i < 8; i++) Vt[sc + 8 + i][srow] = vp[i];
    }
    __syncthreads();

    // S = Q @ K^T  (C-layout: col = fr, rows = g*4 + 0..3)
    f32x4 sf[4];
#pragma unroll
    for (int j = 0; j < 4; j++) sf[j] = f32x4{0.f, 0.f, 0.f, 0.f};
#pragma unroll
    for (int st = 0; st < 2; st++) {
#pragma unroll
      for (int j = 0; j < 4; j++) {
        u32x4 kf = *(const u32x4*)&Ks[j * 16 + fr][st * 32 + g * 8];
        sf[j] = __builtin_amdgcn_mfma_f32_16x16x32_bf16(
            __builtin_bit_cast(bf16x8, qf[st]), __builtin_bit_cast(bf16x8, kf),
            sf[j], 0, 0, 0);
      }
    }

    const bool diag = (kt == qt);
#pragma unroll
    for (int r = 0; r < 4; r++) {
      float pv[4];
      float mx = -1e30f;
#pragma unroll
      for (int j = 0; j < 4; j++) {
        float sv = sf[j][r] * 0.125f;  // 1/sqrt(64)
        if (diag && (j * 16 + fr > wq * 16 + g * 4 + r)) sv = -1e30f;
        pv[j] = sv;
        mx = fmaxf(mx, sv);
      }
      mx = fmaxf(mx, __shfl_xor(mx, 1));
      mx = fmaxf(mx, __shfl_xor(mx, 2));
      mx = fmaxf(mx, __shfl_xor(mx, 4));
      mx = fmaxf(mx, __shfl_xor(mx, 8));
      const float mn = fmaxf(m[r], mx);
      const float corr = __expf(m[r] - mn);
      m[r] = mn;
      float ls = 0.f;
#pragma unroll
      for (int j = 0; j < 4; j++) {
        const float e = __expf(pv[j] - mn);
        Pl[wq][g * 4 + r][j * 16 + fr] = f2bf(e);
        ls += e;
      }
      ls += __shfl_xor(ls, 1);
      ls += __shfl_xor(ls, 2);
      ls += __shfl_xor(ls, 4);
      ls += __shfl_xor(ls, 8);
      l[r] = l[r] * corr + ls;
#pragma unroll
      for (int jd = 0; jd < 4; jd++) of[jd][r] *= corr;
    }

    // O += P @ V  (A-frag from own wave's Pl, B-frag from Vt)
#pragma unroll
    for (int st = 0; st < 2; st++) {
      u32x4 pf = *(const u32x4*)&Pl[wq][fr][st * 32 + g * 8];
#pragma unroll
      for (int jd = 0; jd < 4; jd++) {
        u32x4 vf = *(const u32x4*)&Vt[jd * 16 + fr][st * 32 + g * 8];
        of[jd] = __builtin_amdgcn_mfma_f32_16x16x32_bf16(
            __builtin_bit_cast(bf16x8, pf), __builtin_bit_cast(bf16x8, vf),
            of[jd], 0, 0, 0);
      }
    }
    __syncthreads();
  }

#pragma unroll
  for (int r = 0; r < 4; r++) {
    const float inv = 1.f / l[r];
    const size_t orow =
        (size_t)(b * TSEQ + qt * 64 + wq * 16 + g * 4 + r) * DMODEL + h * DHEAD;
#pragma unroll
    for (int jd = 0; jd < 4; jd++)
      Y[orow + jd * 16 + fr] = f2bf(of[jd][r] * inv);
  }
}

// ---------------------------------------------------------------------------
extern "C" void kernel_launch(void* const* d_in, const int* in_sizes, int n_in,
                              void* d_out, int out_size, void* d_ws, size_t ws_size,
                              hipStream_t stream) {
  const int* idx = (const int*)d_in[0];
  const int* condition = (const int*)d_in[1];
  const float* tok_emb = (const float*)d_in[2];
  const float* cond_emb = (const float*)d_in[3];
  const float* type_emb = (const float*)d_in[4];
  const float* pos_emb = (const float*)d_in[5];
  const float* ln1_g = (const float*)d_in[6];
  const float* ln1_b = (const float*)d_in[7];
  const float* Wq = (const float*)d_in[8];
  const float* bq = (const float*)d_in[9];
  const float* Wk = (const float*)d_in[10];
  const float* bk = (const float*)d_in[11];
  const float* Wv = (const float*)d_in[12];
  const float* bv = (const float*)d_in[13];
  const float* Wp = (const float*)d_in[14];
  const float* bp = (const float*)d_in[15];
  const float* ln2_g = (const float*)d_in[16];
  const float* ln2_b = (const float*)d_in[17];
  const float* W1 = (const float*)d_in[18];
  const float* b1 = (const float*)d_in[19];
  const float* W2 = (const float*)d_in[20];
  const float* b2 = (const float*)d_in[21];
  const float* lnf_g = (const float*)d_in[22];
  const float* lnf_b = (const float*)d_in[23];
  const float* head_w = (const float*)d_in[24];

  const size_t WDD = (size_t)DMODEL * DMODEL;
  const size_t WDF = (size_t)DMODEL * DFF;
  const size_t SD = (size_t)NTOK * DMODEL;

  // workspace layout (~88 MB)
  char* wp = (char*)d_ws;
  auto alloc = [&](size_t bytes) {
    char* r = wp;
    wp += (bytes + 255) & ~(size_t)255;
    return r;
  };
  float* x = (float*)alloc(SD * 4);
  float* h = (float*)alloc(SD * 4);
  unsigned short* hb = (unsigned short*)alloc(SD * 2);
  // shared big buffer: qkv16 [4096][2304] bf16 (18.9MB) then m1b [4096][3072]
  // bf16 (25.2MB) — never live simultaneously (attn finishes before FF1).
  unsigned short* big = (unsigned short*)alloc((size_t)NTOK * DFF * 2);
  unsigned short* qkv16 = big;
  unsigned short* m1b = big;
  unsigned short* yb = (unsigned short*)alloc(SD * 2);
  unsigned short* lw = (unsigned short*)alloc((4 * WDD + 2 * WDF) * 2);
  unsigned short* headt = (unsigned short*)alloc((size_t)VOCAB * DMODEL * 2);
  float* qkvb = (float*)alloc((size_t)NLAYER * QKVD * 4);

  unsigned short* lwQKV = lw;            // 2304 rows x K=768 (Q,K,V contiguous)
  unsigned short* lwP = lw + 3 * WDD;
  unsigned short* lw1 = lw + 4 * WDD;
  unsigned short* lw2 = lw + 4 * WDD + WDF;

  embed_k<<<NTOK, 256, 0, stream>>>(idx, condition, tok_emb, cond_emb,
                                    type_emb, pos_emb, x);
  packb_k<<<NLAYER, 256, 0, stream>>>(bq, bk, bv, qkvb);
  {  // head_w [768][512] -> [512][768] bf16, once
    P4 s{{head_w, nullptr, nullptr, nullptr}};
    transp_k<<<dim3(VOCAB / 64, DMODEL / 64, 1), 256, 0, stream>>>(
        s, headt, DMODEL, VOCAB);
  }

  const dim3 gQKV(NTOK / 128, QKVD / 128);  // 32 x 18 = 576 blocks
  const dim3 gDD64(NTOK / 64, DMODEL / 64); // 64 x 12 = 768 blocks
  const dim3 gDF(NTOK / 128, DFF / 128);    // 32 x 24 = 768 blocks
  const dim3 gDV(NTOK / 64, VOCAB / 64);    // 64 x 8  = 512 blocks

  for (int l = 0; l < NLAYER; l++) {
    {  // JIT convert+transpose this layer's weights into lw
      P4 s{{Wq + l * WDD, Wk + l * WDD, Wv + l * WDD, Wp + l * WDD}};
      transp_k<<<dim3(12, 12, 4), 256, 0, stream>>>(s, lw, DMODEL, DMODEL);
      P4 s1{{W1 + l * WDF, nullptr, nullptr, nullptr}};
      transp_k<<<dim3(48, 12, 1), 256, 0, stream>>>(s1, lw1, DMODEL, DFF);
      P4 s2{{W2 + l * WDF, nullptr, nullptr, nullptr}};
      transp_k<<<dim3(12, 48, 1), 256, 0, stream>>>(s2, lw2, DFF, DMODEL);
    }
    ln_k<true><<<NTOK, 256, 0, stream>>>(x, ln1_g + l * DMODEL,
                                         ln1_b + l * DMODEL, h, hb);
    // fused QKV: [NTOK,768] @ [2304,768]^T -> bf16 [NTOK,2304]
    mm_k<EPQB, 128, 128><<<gQKV, 256, 0, stream>>>(
        hb, lwQKV, qkvb + l * QKVD, nullptr, qkv16, DMODEL, QKVD);
    attn_mfma_k<<<dim3(8, NHEAD, 8), 256, 0, stream>>>(qkv16, yb);
    // x = h + y @ Wp + bp  (residual base is post-ln1 h, per reference quirk)
    mm_k<EPRES, 64, 64><<<gDD64, 256, 0, stream>>>(
        yb, lwP, bp + l * DMODEL, h, x, DMODEL, DMODEL);
    ln_k<false><<<NTOK, 256, 0, stream>>>(x, ln2_g + l * DMODEL,
                                          ln2_b + l * DMODEL, nullptr, hb);
    mm_k<EPGELU, 128, 128><<<gDF, 256, 0, stream>>>(
        hb, lw1, b1 + l * DFF, nullptr, m1b, DMODEL, DFF);
    // x = x + m1 @ W2 + b2 (in-place: each element read+written by same thread)
    mm_k<EPRES, 64, 64><<<gDD64, 256, 0, stream>>>(
        m1b, lw2, b2 + l * DMODEL, x, x, DFF, DMODEL);
  }

  ln_k<false><<<NTOK, 256, 0, stream>>>(x, lnf_g, lnf_b, nullptr, hb);
  mm_k<EPHEAD, 64, 64><<<gDV, 256, 0, stream>>>(
      hb, headt, nullptr, nullptr, d_out, DMODEL, VOCAB);
}

// Round 6
// 1559.270 us; speedup vs baseline: 1.8112x; 1.0725x over previous
//
#include <hip/hip_runtime.h>
#include <hip/hip_bf16.h>
#include <cstddef>
#include <cstdint>

// ---------------------------------------------------------------------------
// GPT forward: bf16 MFMA GEMMs (3-buffer counted-vmcnt pipeline) + bf16 MFMA
// flash attention; fp32 LN/softmax/residual.
// B=8, T=512 (incl. cond token), D=768, H=12, dh=64, L=8, V=512, 4D=3072
// ---------------------------------------------------------------------------

#define NTOK 4096
#define TSEQ 512
#define DMODEL 768
#define DFF 3072
#define NHEAD 12
#define DHEAD 64
#define NLAYER 8
#define VOCAB 512
#define QKVD 2304  // 3*DMODEL fused QKV width

typedef __attribute__((ext_vector_type(8))) __bf16 bf16x8;
typedef __attribute__((ext_vector_type(4))) float f32x4;
typedef __attribute__((ext_vector_type(4))) unsigned int u32x4;
typedef __attribute__((ext_vector_type(4))) unsigned short u16x4;

__device__ __forceinline__ unsigned short f2bf(float f) {
  union { float f; unsigned int u; } v; v.f = f;
  return (unsigned short)((v.u + 0x7FFFu + ((v.u >> 16) & 1u)) >> 16);  // RNE
}

__device__ __forceinline__ float gelu_exact(float x) {
  return 0.5f * x * (1.f + erff(x * 0.70710678118654752f));
}

// direct global->LDS, 16B/lane, wave-uniform LDS base + lane*16
__device__ __forceinline__ void gload_lds16(const void* g, void* lds) {
  __builtin_amdgcn_global_load_lds(
      reinterpret_cast<__attribute__((address_space(1))) void*>(
          reinterpret_cast<uintptr_t>(g)),
      reinterpret_cast<__attribute__((address_space(3))) void*>(
          reinterpret_cast<uintptr_t>(lds)),
      16, 0, 0);
}

template <int N>
__device__ __forceinline__ void waitvm() {
  if constexpr (N == 0) asm volatile("s_waitcnt vmcnt(0)" ::: "memory");
  else if constexpr (N == 2) asm volatile("s_waitcnt vmcnt(2)" ::: "memory");
  else if constexpr (N == 3) asm volatile("s_waitcnt vmcnt(3)" ::: "memory");
  else if constexpr (N == 4) asm volatile("s_waitcnt vmcnt(4)" ::: "memory");
  else static_assert(N == 0, "unsupported vmcnt");
}

// ---------------- embedding (fp32) ----------------
__global__ __launch_bounds__(256) void embed_k(
    const int* __restrict__ idx, const int* __restrict__ cond,
    const float* __restrict__ tok, const float* __restrict__ ce,
    const float* __restrict__ te, const float* __restrict__ pe,
    float* __restrict__ X) {
  int row = blockIdx.x;  // b*512 + t
  int b = row >> 9, t = row & 511;
  int tid = threadIdx.x;
  const float* src = (t == 0) ? (ce + (size_t)cond[b] * DMODEL)
                              : (tok + (size_t)idx[b * 511 + t - 1] * DMODEL);
  const float* ty = te + (t != 0 ? DMODEL : 0);
  const float* pp = pe + (size_t)t * DMODEL;
  float* dst = X + (size_t)row * DMODEL;
#pragma unroll
  for (int i = 0; i < 3; i++) {
    int d = tid + i * 256;
    dst[d] = src[d] + pp[d] + ty[d];
  }
}

// ---------------- layernorm: fp32 in, bf16 out (+optional fp32 out) --------
template <bool F32OUT>
__global__ __launch_bounds__(256) void ln_k(
    const float* __restrict__ X, const float* __restrict__ g,
    const float* __restrict__ bta, float* __restrict__ O,
    unsigned short* __restrict__ Ob) {
  const int row = blockIdx.x;
  const int tid = threadIdx.x;
  const float* x = X + (size_t)row * DMODEL;
  float v0 = x[tid], v1 = x[tid + 256], v2 = x[tid + 512];
  float s = v0 + v1 + v2;
  float ss = v0 * v0 + v1 * v1 + v2 * v2;
#pragma unroll
  for (int o = 32; o > 0; o >>= 1) {
    s += __shfl_down(s, o);
    ss += __shfl_down(ss, o);
  }
  __shared__ float sm[8];
  const int wid = tid >> 6, lane = tid & 63;
  if (lane == 0) { sm[wid] = s; sm[wid + 4] = ss; }
  __syncthreads();
  float st = sm[0] + sm[1] + sm[2] + sm[3];
  float sst = sm[4] + sm[5] + sm[6] + sm[7];
  float mean = st * (1.f / DMODEL);
  float var = sst * (1.f / DMODEL) - mean * mean;
  float rstd = rsqrtf(var + 1e-5f);
  float y0 = (v0 - mean) * rstd * g[tid] + bta[tid];
  float y1 = (v1 - mean) * rstd * g[tid + 256] + bta[tid + 256];
  float y2 = (v2 - mean) * rstd * g[tid + 512] + bta[tid + 512];
  if (F32OUT) {
    float* o = O + (size_t)row * DMODEL;
    o[tid] = y0; o[tid + 256] = y1; o[tid + 512] = y2;
  }
  unsigned short* ob = Ob + (size_t)row * DMODEL;
  ob[tid] = f2bf(y0); ob[tid + 256] = f2bf(y1); ob[tid + 512] = f2bf(y2);
}

// ---------------- weight convert+transpose: fp32 [K][N] -> bf16 [N][K] -----
struct P4 { const float* p[4]; };

__global__ __launch_bounds__(256) void transp_k(P4 src,
                                                unsigned short* __restrict__ out,
                                                int K, int N) {
  __shared__ alignas(16) float Ls[64][65];
  const float* W = src.p[blockIdx.z];
  unsigned short* o = out + (size_t)blockIdx.z * K * N;
  const int tid = threadIdx.x;
  const int n0 = blockIdx.x * 64, k0 = blockIdx.y * 64;
  const int r = tid >> 4, c4 = (tid & 15) * 4;
#pragma unroll
  for (int i = 0; i < 4; i++) {
    const int kk = r + i * 16;
    const float4 v = *(const float4*)(W + (size_t)(k0 + kk) * N + n0 + c4);
    Ls[c4 + 0][kk] = v.x;
    Ls[c4 + 1][kk] = v.y;
    Ls[c4 + 2][kk] = v.z;
    Ls[c4 + 3][kk] = v.w;
  }
  __syncthreads();
#pragma unroll
  for (int i = 0; i < 4; i++) {
    const int nn = r + i * 16;
    u16x4 q;
    q.x = f2bf(Ls[nn][c4 + 0]);
    q.y = f2bf(Ls[nn][c4 + 1]);
    q.z = f2bf(Ls[nn][c4 + 2]);
    q.w = f2bf(Ls[nn][c4 + 3]);
    *(u16x4*)(o + (size_t)(n0 + nn) * K + k0 + c4) = q;
  }
}

// ---------------- pack per-layer QKV biases: [L][2304] ----------------
__global__ __launch_bounds__(256) void packb_k(const float* __restrict__ bq,
                                               const float* __restrict__ bk,
                                               const float* __restrict__ bv,
                                               float* __restrict__ o) {
  const int l = blockIdx.x, tid = threadIdx.x;
#pragma unroll
  for (int i = 0; i < 9; i++) {
    int n = tid + i * 256;
    float v = (n < 768) ? bq[l * 768 + n]
                        : (n < 1536) ? bk[l * 768 + n - 768]
                                     : bv[l * 768 + n - 1536];
    o[l * QKVD + n] = v;
  }
}

// ---------------- bf16 MFMA GEMM, 3-buffer counted-vmcnt pipeline ----------
// C[M,N] = A[M,K](bf16) @ Bt[N,K](bf16)^T, fp32 accumulate.
// Per K-step (BK=32): ds_read frags(t) -> STAGE(t+2) -> MFMA(t) ->
// s_waitcnt vmcnt(G) [tile t+1 landed; never 0 mid-loop] -> s_barrier.
// Swizzle: 16B chunk ^= (row>>1)&3 on BOTH pre-swizzled global source and the
// ds_read address (rule #21) -> bank-group (row&1)*4+(ch^((row>>1)&3)) covers
// all 8 groups per 8 rows -> 2-way (free, m136).
#define BK 32

constexpr int EPQ = 0;     // C f32 = acc + bias
constexpr int EPRES = 1;   // C f32 = acc + bias + res
constexpr int EPGELU = 2;  // C bf16 = gelu(acc + bias)
constexpr int EPHEAD = 3;  // C f32, row b*511+t-1 (skip t==0), no bias
constexpr int EPQB = 4;    // C bf16 = acc + bias

template <int EP, int TBM, int TBN>
__global__ __launch_bounds__(256) void mm_k(
    const unsigned short* __restrict__ A, const unsigned short* __restrict__ Bt,
    const float* __restrict__ bias, const float* __restrict__ res,
    void* __restrict__ Cv, int K, int N) {
  __shared__ alignas(16) unsigned short As[3][TBM * BK];
  __shared__ alignas(16) unsigned short Bs[3][TBN * BK];
  constexpr int WM = TBM / 2, WN = TBN / 2;   // per-wave output tile
  constexpr int MI = WM / 16, NJ = WN / 16;   // fragment repeats
  constexpr int GA = TBM / 64, GB = TBN / 64; // staging issues per wave
  constexpr int G = GA + GB;
  const int tid = threadIdx.x;
  const int lane = tid & 63, wid = tid >> 6;
  const int wr = wid >> 1, wc = wid & 1;
  const int m0 = blockIdx.x * TBM, n0 = blockIdx.y * TBN;

  f32x4 acc[MI][NJ];
#pragma unroll
  for (int i = 0; i < MI; i++)
#pragma unroll
    for (int j = 0; j < NJ; j++) acc[i][j] = f32x4{0.f, 0.f, 0.f, 0.f};

  const int srow = lane >> 2;                        // staging row in 16-row issue
  const int gch = (lane & 3) ^ ((srow >> 1) & 3);    // pre-swizzled 16B chunk
  const size_t rb = (size_t)K * 2;                   // row bytes
  const int fr = lane & 15, ks = lane >> 4;          // fragment row, k-subchunk
  const int NKI = K / BK;

  auto stage = [&](int kt, int slot) {
    const size_t koff = (size_t)kt * BK * 2;
#pragma unroll
    for (int t = 0; t < GA; t++) {
      const int rr = wid * (TBM / 4) + t * 16;       // wave-uniform row base
      gload_lds16((const char*)A + (size_t)(m0 + rr + srow) * rb + koff + gch * 16,
                  &As[slot][rr * BK]);
    }
#pragma unroll
    for (int t = 0; t < GB; t++) {
      const int rr = wid * (TBN / 4) + t * 16;
      gload_lds16((const char*)Bt + (size_t)(n0 + rr + srow) * rb + koff + gch * 16,
                  &Bs[slot][rr * BK]);
    }
  };

  // prologue: tiles 0,1 in flight; wait tile 0 only
  stage(0, 0);
  stage(1, 1);
  waitvm<G>();
  __builtin_amdgcn_s_barrier();
  __builtin_amdgcn_sched_barrier(0);

  int cur = 0;
  for (int t = 0; t < NKI; ++t) {
    const unsigned short* Ab = &As[cur][0];
    const unsigned short* Bb = &Bs[cur][0];
    u32x4 ar[MI], br[NJ];
#pragma unroll
    for (int i = 0; i < MI; i++) {
      const int ra = wr * WM + i * 16 + fr;
      ar[i] = *(const u32x4*)((const char*)Ab + ra * 64 +
                              ((ks ^ ((ra >> 1) & 3)) << 4));
    }
#pragma unroll
    for (int j = 0; j < NJ; j++) {
      const int rbw = wc * WN + j * 16 + fr;
      br[j] = *(const u32x4*)((const char*)Bb + rbw * 64 +
                              ((ks ^ ((rbw >> 1) & 3)) << 4));
    }
    const int nslot = (cur >= 1) ? cur - 1 : cur + 2;  // (cur+2)%3
    const bool pf = (t + 2 < NKI);
    if (pf) stage(t + 2, nslot);
    __builtin_amdgcn_s_setprio(1);
#pragma unroll
    for (int i = 0; i < MI; i++)
#pragma unroll
      for (int j = 0; j < NJ; j++)
        acc[i][j] = __builtin_amdgcn_mfma_f32_16x16x32_bf16(
            __builtin_bit_cast(bf16x8, ar[i]), __builtin_bit_cast(bf16x8, br[j]),
            acc[i][j], 0, 0, 0);
    __builtin_amdgcn_s_setprio(0);
    if (pf) waitvm<G>(); else waitvm<0>();
    __builtin_amdgcn_sched_barrier(0);
    __builtin_amdgcn_s_barrier();
    __builtin_amdgcn_sched_barrier(0);
    cur = (cur == 2) ? 0 : cur + 1;
  }

  // epilogue: D[row=(lane>>4)*4+r][col=lane&15] per 16x16 fragment (m89)
#pragma unroll
  for (int i = 0; i < MI; i++) {
#pragma unroll
    for (int j = 0; j < NJ; j++) {
      const int n = n0 + wc * WN + j * 16 + fr;
      float bv = 0.f;
      if (EP != EPHEAD) bv = bias[n];
#pragma unroll
      for (int r = 0; r < 4; r++) {
        const int m = m0 + wr * WM + i * 16 + ks * 4 + r;
        float v = acc[i][j][r] + bv;
        if (EP == EPRES) v += res[(size_t)m * N + n];
        if (EP == EPGELU) {
          ((unsigned short*)Cv)[(size_t)m * N + n] = f2bf(gelu_exact(v));
        } else if (EP == EPQB) {
          ((unsigned short*)Cv)[(size_t)m * N + n] = f2bf(v);
        } else if (EP == EPHEAD) {
          const int bb = m >> 9, tt = m & 511;
          if (tt)
            ((float*)Cv)[(size_t)(bb * 511 + tt - 1) * N + n] = v;
        } else {
          ((float*)Cv)[(size_t)m * N + n] = v;
        }
      }
    }
  }
}

// ---------------- bf16 MFMA flash attention ----------------
// grid (8 qtiles, 12 heads, 8 batch), 256 thr = 4 waves; wave wq owns q-rows
// [qt*64 + wq*16, +16).
__global__ __launch_bounds__(256) void attn_mfma_k(
    const unsigned short* __restrict__ QKV, unsigned short* __restrict__ Y) {
  __shared__ alignas(16) unsigned short Ks[64][72];
  __shared__ alignas(16) unsigned short Vt[64][72];
  __shared__ alignas(16) unsigned short Pl[4][16][72];
  const int qt = 7 - (int)blockIdx.x;  // heavy blocks first (less tail)
  const int h = blockIdx.y, b = blockIdx.z;
  const int tid = threadIdx.x;
  const int lane = tid & 63, wq = tid >> 6;
  const int fr = lane & 15, g = lane >> 4;

  const size_t qrow =
      (size_t)(b * TSEQ + qt * 64 + wq * 16 + fr) * QKVD + h * DHEAD;
  u32x4 qf[2];
  qf[0] = *(const u32x4*)(QKV + qrow + g * 8);
  qf[1] = *(const u32x4*)(QKV + qrow + 32 + g * 8);

  f32x4 of[4];
  float m[4], l[4];
#pragma unroll
  for (int jd = 0; jd < 4; jd++) of[jd] = f32x4{0.f, 0.f, 0.f, 0.f};
#pragma unroll
  for (int r = 0; r < 4; r++) { m[r] = -1e30f; l[r] = 0.f; }

  const int srow = tid >> 2, sc = (tid & 3) * 16;  // staging row / 16-col chunk

  for (int kt = 0; kt <= qt; kt++) {
    {  // stage K tile and transposed V tile
      const size_t kr = (size_t)(b * TSEQ + kt * 64 + srow) * QKVD + h * DHEAD;
      u32x4 k0 = *(const u32x4*)(QKV + kr + DMODEL + sc);
      u32x4 k1 = *(const u32x4*)(QKV + kr + DMODEL + sc + 8);
      *(u32x4*)&Ks[srow][sc] = k0;
      *(u32x4*)&Ks[srow][sc + 8] = k1;
      u32x4 v0 = *(const u32x4*)(QKV + kr + 2 * DMODEL + sc);
      u32x4 v1 = *(const u32x4*)(QKV + kr + 2 * DMODEL + sc + 8);
      const unsigned short* vp = (const unsigned short*)&v0;
#pragma unroll
      for (int i = 0; i < 8; i++) Vt[sc + i][srow] = vp[i];
      vp = (const unsigned short*)&v1;
#pragma unroll
      for (int i = 0; i < 8; i++) Vt[sc + 8 + i][srow] = vp[i];
    }
    __syncthreads();

    // S = Q @ K^T  (C-layout: col = fr, rows = g*4 + 0..3)
    f32x4 sf[4];
#pragma unroll
    for (int j = 0; j < 4; j++) sf[j] = f32x4{0.f, 0.f, 0.f, 0.f};
#pragma unroll
    for (int st = 0; st < 2; st++) {
#pragma unroll
      for (int j = 0; j < 4; j++) {
        u32x4 kf = *(const u32x4*)&Ks[j * 16 + fr][st * 32 + g * 8];
        sf[j] = __builtin_amdgcn_mfma_f32_16x16x32_bf16(
            __builtin_bit_cast(bf16x8, qf[st]), __builtin_bit_cast(bf16x8, kf),
            sf[j], 0, 0, 0);
      }
    }

    const bool diag = (kt == qt);
#pragma unroll
    for (int r = 0; r < 4; r++) {
      float pv[4];
      float mx = -1e30f;
#pragma unroll
      for (int j = 0; j < 4; j++) {
        float sv = sf[j][r] * 0.125f;  // 1/sqrt(64)
        if (diag && (j * 16 + fr > wq * 16 + g * 4 + r)) sv = -1e30f;
        pv[j] = sv;
        mx = fmaxf(mx, sv);
      }
      mx = fmaxf(mx, __shfl_xor(mx, 1));
      mx = fmaxf(mx, __shfl_xor(mx, 2));
      mx = fmaxf(mx, __shfl_xor(mx, 4));
      mx = fmaxf(mx, __shfl_xor(mx, 8));
      const float mn = fmaxf(m[r], mx);
      const float corr = __expf(m[r] - mn);
      m[r] = mn;
      float ls = 0.f;
#pragma unroll
      for (int j = 0; j < 4; j++) {
        const float e = __expf(pv[j] - mn);
        Pl[wq][g * 4 + r][j * 16 + fr] = f2bf(e);
        ls += e;
      }
      ls += __shfl_xor(ls, 1);
      ls += __shfl_xor(ls, 2);
      ls += __shfl_xor(ls, 4);
      ls += __shfl_xor(ls, 8);
      l[r] = l[r] * corr + ls;
#pragma unroll
      for (int jd = 0; jd < 4; jd++) of[jd][r] *= corr;
    }

    // O += P @ V
#pragma unroll
    for (int st = 0; st < 2; st++) {
      u32x4 pf = *(const u32x4*)&Pl[wq][fr][st * 32 + g * 8];
#pragma unroll
      for (int jd = 0; jd < 4; jd++) {
        u32x4 vf = *(const u32x4*)&Vt[jd * 16 + fr][st * 32 + g * 8];
        of[jd] = __builtin_amdgcn_mfma_f32_16x16x32_bf16(
            __builtin_bit_cast(bf16x8, pf), __builtin_bit_cast(bf16x8, vf),
            of[jd], 0, 0, 0);
      }
    }
    __syncthreads();
  }

#pragma unroll
  for (int r = 0; r < 4; r++) {
    const float inv = 1.f / l[r];
    const size_t orow =
        (size_t)(b * TSEQ + qt * 64 + wq * 16 + g * 4 + r) * DMODEL + h * DHEAD;
#pragma unroll
    for (int jd = 0; jd < 4; jd++)
      Y[orow + jd * 16 + fr] = f2bf(of[jd][r] * inv);
  }
}

// ---------------------------------------------------------------------------
extern "C" void kernel_launch(void* const* d_in, const int* in_sizes, int n_in,
                              void* d_out, int out_size, void* d_ws, size_t ws_size,
                              hipStream_t stream) {
  const int* idx = (const int*)d_in[0];
  const int* condition = (const int*)d_in[1];
  const float* tok_emb = (const float*)d_in[2];
  const float* cond_emb = (const float*)d_in[3];
  const float* type_emb = (const float*)d_in[4];
  const float* pos_emb = (const float*)d_in[5];
  const float* ln1_g = (const float*)d_in[6];
  const float* ln1_b = (const float*)d_in[7];
  const float* Wq = (const float*)d_in[8];
  const float* bq = (const float*)d_in[9];
  const float* Wk = (const float*)d_in[10];
  const float* bk = (const float*)d_in[11];
  const float* Wv = (const float*)d_in[12];
  const float* bv = (const float*)d_in[13];
  const float* Wp = (const float*)d_in[14];
  const float* bp = (const float*)d_in[15];
  const float* ln2_g = (const float*)d_in[16];
  const float* ln2_b = (const float*)d_in[17];
  const float* W1 = (const float*)d_in[18];
  const float* b1 = (const float*)d_in[19];
  const float* W2 = (const float*)d_in[20];
  const float* b2 = (const float*)d_in[21];
  const float* lnf_g = (const float*)d_in[22];
  const float* lnf_b = (const float*)d_in[23];
  const float* head_w = (const float*)d_in[24];

  const size_t WDD = (size_t)DMODEL * DMODEL;
  const size_t WDF = (size_t)DMODEL * DFF;
  const size_t SD = (size_t)NTOK * DMODEL;

  // workspace layout (~88 MB)
  char* wp = (char*)d_ws;
  auto alloc = [&](size_t bytes) {
    char* r = wp;
    wp += (bytes + 255) & ~(size_t)255;
    return r;
  };
  float* x = (float*)alloc(SD * 4);
  float* h = (float*)alloc(SD * 4);
  unsigned short* hb = (unsigned short*)alloc(SD * 2);
  // shared big buffer: qkv16 [4096][2304] bf16 then m1b [4096][3072] bf16 —
  // never live simultaneously (attn finishes before FF1).
  unsigned short* big = (unsigned short*)alloc((size_t)NTOK * DFF * 2);
  unsigned short* qkv16 = big;
  unsigned short* m1b = big;
  unsigned short* yb = (unsigned short*)alloc(SD * 2);
  unsigned short* lw = (unsigned short*)alloc((4 * WDD + 2 * WDF) * 2);
  unsigned short* headt = (unsigned short*)alloc((size_t)VOCAB * DMODEL * 2);
  float* qkvb = (float*)alloc((size_t)NLAYER * QKVD * 4);

  unsigned short* lwQKV = lw;            // 2304 rows x K=768 (Q,K,V contiguous)
  unsigned short* lwP = lw + 3 * WDD;
  unsigned short* lw1 = lw + 4 * WDD;
  unsigned short* lw2 = lw + 4 * WDD + WDF;

  embed_k<<<NTOK, 256, 0, stream>>>(idx, condition, tok_emb, cond_emb,
                                    type_emb, pos_emb, x);
  packb_k<<<NLAYER, 256, 0, stream>>>(bq, bk, bv, qkvb);
  {  // head_w [768][512] -> [512][768] bf16, once
    P4 s{{head_w, nullptr, nullptr, nullptr}};
    transp_k<<<dim3(VOCAB / 64, DMODEL / 64, 1), 256, 0, stream>>>(
        s, headt, DMODEL, VOCAB);
  }

  const dim3 gQKV(NTOK / 128, QKVD / 128);  // 32 x 18 = 576 blocks
  const dim3 gDD(NTOK / 128, DMODEL / 64);  // 32 x 12 = 384 blocks (128x64)
  const dim3 gDF(NTOK / 128, DFF / 128);    // 32 x 24 = 768 blocks
  const dim3 gDV(NTOK / 128, VOCAB / 64);   // 32 x 8  = 256 blocks (128x64)

  for (int l = 0; l < NLAYER; l++) {
    {  // JIT convert+transpose this layer's weights into lw
      P4 s{{Wq + l * WDD, Wk + l * WDD, Wv + l * WDD, Wp + l * WDD}};
      transp_k<<<dim3(12, 12, 4), 256, 0, stream>>>(s, lw, DMODEL, DMODEL);
      P4 s1{{W1 + l * WDF, nullptr, nullptr, nullptr}};
      transp_k<<<dim3(48, 12, 1), 256, 0, stream>>>(s1, lw1, DMODEL, DFF);
      P4 s2{{W2 + l * WDF, nullptr, nullptr, nullptr}};
      transp_k<<<dim3(12, 48, 1), 256, 0, stream>>>(s2, lw2, DFF, DMODEL);
    }
    ln_k<true><<<NTOK, 256, 0, stream>>>(x, ln1_g + l * DMODEL,
                                         ln1_b + l * DMODEL, h, hb);
    // fused QKV: [NTOK,768] @ [2304,768]^T -> bf16 [NTOK,2304]
    mm_k<EPQB, 128, 128><<<gQKV, 256, 0, stream>>>(
        hb, lwQKV, qkvb + l * QKVD, nullptr, qkv16, DMODEL, QKVD);
    attn_mfma_k<<<dim3(8, NHEAD, 8), 256, 0, stream>>>(qkv16, yb);
    // x = h + y @ Wp + bp  (residual base is post-ln1 h, per reference quirk)
    mm_k<EPRES, 128, 64><<<gDD, 256, 0, stream>>>(
        yb, lwP, bp + l * DMODEL, h, x, DMODEL, DMODEL);
    ln_k<false><<<NTOK, 256, 0, stream>>>(x, ln2_g + l * DMODEL,
                                          ln2_b + l * DMODEL, nullptr, hb);
    mm_k<EPGELU, 128, 128><<<gDF, 256, 0, stream>>>(
        hb, lw1, b1 + l * DFF, nullptr, m1b, DMODEL, DFF);
    // x = x + m1 @ W2 + b2 (in-place: each element read+written by same thread)
    mm_k<EPRES, 128, 64><<<gDD, 256, 0, stream>>>(
        m1b, lw2, b2 + l * DMODEL, x, x, DFF, DMODEL);
  }

  ln_k<false><<<NTOK, 256, 0, stream>>>(x, lnf_g, lnf_b, nullptr, hb);
  mm_k<EPHEAD, 128, 64><<<gDV, 256, 0, stream>>>(
      hb, headt, nullptr, nullptr, d_out, DMODEL, VOCAB);
}